// Round 1
// baseline (291.776 us; speedup 1.0000x reference)
//
#include <hip/hip_runtime.h>
#include <stdint.h>

// Problem constants
#define NN 4096
#define KSEL 1677721u            // int(4096*4096*0.1)
#define INV_SQRT_DK 0.17677669529663687f  // 1/sqrt(32)

// Workspace layout (bytes)
#define OFF_QC 0                          // 4096*128 fp32 = 2 MB
#define OFF_KC (4096*128*4)               // 2 MB
#define OFF_HA (2*4096*128*4)             // hist level0: 4096 u32
#define OFF_HB (OFF_HA + 4096*4)          // hist level1: 4096 u32
#define OFF_HC (OFF_HB + 4096*4)          // hist level2: 256 u32
#define OFF_ST (OFF_HC + 256*4)           // state: 4 u32
#define ZERO_BYTES ((OFF_ST + 16) - OFF_HA)

// ---------------------------------------------------------------------------
// 1) Projection: Qcat[n][b*32+d] = sum_{t,f} x[b,f,n,t] * W_Q[t*64+f][d]
//    (Q gets the 1/sqrt(32) fold). Block = (b, 64-n tile), 256 threads.
//    x[b,f,n0:n0+64,0:12] is 768 contiguous floats -> coalesced LDS stage.
//    W reads are wave-uniform (readfirstlane) -> scalar loads.
// ---------------------------------------------------------------------------
__global__ __launch_bounds__(256) void proj_kernel(
    const float* __restrict__ x, const float* __restrict__ WQ,
    const float* __restrict__ WK, float* __restrict__ Qc, float* __restrict__ Kc)
{
    __shared__ float xs[64 * 13];   // pad 12->13 to break bank conflicts
    const int b   = blockIdx.x >> 6;
    const int n0  = (blockIdx.x & 63) << 6;
    const int tid = threadIdx.x;
    const int nl  = tid & 63;
    const int cg  = __builtin_amdgcn_readfirstlane(tid >> 6); // wave-uniform 0..3
    const int cb  = (cg & 1) << 4;
    const float* __restrict__ Wp = (cg < 2) ? WQ : WK;

    float acc[16];
#pragma unroll
    for (int j = 0; j < 16; ++j) acc[j] = 0.f;

    const float* gx0 = x + (size_t)b * 3145728 + (size_t)n0 * 12;

    for (int f = 0; f < 64; ++f) {
        __syncthreads();
        const float* gx = gx0 + (size_t)f * 49152;
#pragma unroll
        for (int j = 0; j < 3; ++j) {
            int idx = tid + 256 * j;         // 0..767 contiguous
            int nn_ = idx / 12;
            int tt  = idx - nn_ * 12;
            xs[nn_ * 13 + tt] = gx[idx];
        }
        __syncthreads();
        for (int t = 0; t < 12; ++t) {
            float xv = xs[nl * 13 + t];
            const float* wr = Wp + (size_t)((t << 6) + f) * 32 + cb; // uniform addr
#pragma unroll
            for (int j = 0; j < 16; ++j) acc[j] = fmaf(xv, wr[j], acc[j]);
        }
    }

    const float scale = (cg < 2) ? INV_SQRT_DK : 1.0f;
    float* dst = ((cg < 2) ? Qc : Kc) + (size_t)(n0 + nl) * 128 + (b << 5) + cb;
#pragma unroll
    for (int j = 0; j < 16; ++j) dst[j] = acc[j] * scale;
}

// ---------------------------------------------------------------------------
// 2) S = Qc @ Kc^T  (4096x4096x128 fp32). 128x128 tile per 256-thread block,
//    8x8 acc per thread. LDS stored k-major with pad 132 (=4*33).
// ---------------------------------------------------------------------------
__global__ __launch_bounds__(256) void gemm_kernel(
    const float* __restrict__ Qc, const float* __restrict__ Kc,
    float* __restrict__ S)
{
    __shared__ float Qs[16 * 132];
    __shared__ float Ks[16 * 132];
    const int bi = blockIdx.x >> 5, bj = blockIdx.x & 31;
    const int tid = threadIdx.x;
    const int tr = tid >> 4, tc = tid & 15;
    const int kc4 = tid & 3, nr = tid >> 2;

    float acc[8][8];
#pragma unroll
    for (int i = 0; i < 8; ++i)
#pragma unroll
        for (int j = 0; j < 8; ++j) acc[i][j] = 0.f;

    const float* qbase = Qc + (size_t)(bi * 128) * 128;
    const float* kbase = Kc + (size_t)(bj * 128) * 128;

    for (int k0 = 0; k0 < 128; k0 += 16) {
        __syncthreads();
#pragma unroll
        for (int h = 0; h < 2; ++h) {
            int row = nr + h * 64;
            float4 q = *(const float4*)(qbase + (size_t)row * 128 + k0 + kc4 * 4);
            float4 kv = *(const float4*)(kbase + (size_t)row * 128 + k0 + kc4 * 4);
            Qs[(kc4 * 4 + 0) * 132 + row] = q.x;
            Qs[(kc4 * 4 + 1) * 132 + row] = q.y;
            Qs[(kc4 * 4 + 2) * 132 + row] = q.z;
            Qs[(kc4 * 4 + 3) * 132 + row] = q.w;
            Ks[(kc4 * 4 + 0) * 132 + row] = kv.x;
            Ks[(kc4 * 4 + 1) * 132 + row] = kv.y;
            Ks[(kc4 * 4 + 2) * 132 + row] = kv.z;
            Ks[(kc4 * 4 + 3) * 132 + row] = kv.w;
        }
        __syncthreads();
#pragma unroll
        for (int kk = 0; kk < 16; ++kk) {
            float4 a0 = *(const float4*)&Qs[kk * 132 + tr * 4];
            float4 a1 = *(const float4*)&Qs[kk * 132 + 64 + tr * 4];
            float4 b0 = *(const float4*)&Ks[kk * 132 + tc * 4];
            float4 b1 = *(const float4*)&Ks[kk * 132 + 64 + tc * 4];
            float a[8] = {a0.x, a0.y, a0.z, a0.w, a1.x, a1.y, a1.z, a1.w};
            float bb[8] = {b0.x, b0.y, b0.z, b0.w, b1.x, b1.y, b1.z, b1.w};
#pragma unroll
            for (int i = 0; i < 8; ++i)
#pragma unroll
                for (int j = 0; j < 8; ++j) acc[i][j] = fmaf(a[i], bb[j], acc[i][j]);
        }
    }
#pragma unroll
    for (int i = 0; i < 8; ++i) {
        int row = bi * 128 + tr * 4 + (i & 3) + ((i >> 2) << 6);
        float* dst = S + (size_t)row * NN + bj * 128;
        *(float4*)(dst + tc * 4)      = make_float4(acc[i][0], acc[i][1], acc[i][2], acc[i][3]);
        *(float4*)(dst + 64 + tc * 4) = make_float4(acc[i][4], acc[i][5], acc[i][6], acc[i][7]);
    }
}

// ---------------------------------------------------------------------------
// 3) Row softmax in place. One block per row; row staged in LDS.
// ---------------------------------------------------------------------------
__global__ __launch_bounds__(256) void softmax_kernel(float* __restrict__ S)
{
    __shared__ float xs[NN];
    __shared__ float red[8];
    const int tid = threadIdx.x;
    float* r = S + (size_t)blockIdx.x * NN;

    float lmax = -3.4e38f;
    for (int i = tid; i < NN / 4; i += 256) {
        float4 v = ((const float4*)r)[i];
        ((float4*)xs)[i] = v;
        lmax = fmaxf(fmaxf(fmaxf(lmax, v.x), v.y), fmaxf(v.z, v.w));
    }
#pragma unroll
    for (int off = 32; off; off >>= 1) lmax = fmaxf(lmax, __shfl_xor(lmax, off));
    if ((tid & 63) == 0) red[tid >> 6] = lmax;
    __syncthreads();
    const float m = fmaxf(fmaxf(red[0], red[1]), fmaxf(red[2], red[3]));

    float lsum = 0.f;
    for (int i = tid; i < NN / 4; i += 256) {
        float4 v = ((float4*)xs)[i];
        v.x = __expf(v.x - m); v.y = __expf(v.y - m);
        v.z = __expf(v.z - m); v.w = __expf(v.w - m);
        ((float4*)xs)[i] = v;
        lsum += v.x + v.y + v.z + v.w;
    }
#pragma unroll
    for (int off = 32; off; off >>= 1) lsum += __shfl_xor(lsum, off);
    if ((tid & 63) == 0) red[4 + (tid >> 6)] = lsum;
    __syncthreads();
    const float inv = 1.0f / (red[4] + red[5] + red[6] + red[7]);

    for (int i = tid; i < NN / 4; i += 256) {
        float4 v = ((float4*)xs)[i];
        v.x *= inv; v.y *= inv; v.z *= inv; v.w *= inv;
        ((float4*)r)[i] = v;
    }
}

// ---------------------------------------------------------------------------
// 4) Radix-select: histogram passes (positive floats -> uint order-preserving)
// ---------------------------------------------------------------------------
__global__ __launch_bounds__(256) void hist_kernel(
    const uint4* __restrict__ v4, unsigned n4, unsigned* __restrict__ gh,
    int level, const unsigned* __restrict__ st)
{
    __shared__ unsigned h[4096];
    const int nb = (level == 2) ? 256 : 4096;
    for (int i = threadIdx.x; i < nb; i += 256) h[i] = 0;
    const unsigned prefix = (level > 0) ? st[0] : 0u;
    __syncthreads();
    const unsigned stride = gridDim.x * blockDim.x;
    for (unsigned i = blockIdx.x * blockDim.x + threadIdx.x; i < n4; i += stride) {
        uint4 v = v4[i];
        if (level == 0) {
            atomicAdd(&h[v.x >> 20], 1u); atomicAdd(&h[v.y >> 20], 1u);
            atomicAdd(&h[v.z >> 20], 1u); atomicAdd(&h[v.w >> 20], 1u);
        } else if (level == 1) {
            if ((v.x >> 20) == prefix) atomicAdd(&h[(v.x >> 8) & 0xFFFu], 1u);
            if ((v.y >> 20) == prefix) atomicAdd(&h[(v.y >> 8) & 0xFFFu], 1u);
            if ((v.z >> 20) == prefix) atomicAdd(&h[(v.z >> 8) & 0xFFFu], 1u);
            if ((v.w >> 20) == prefix) atomicAdd(&h[(v.w >> 8) & 0xFFFu], 1u);
        } else {
            if ((v.x >> 8) == prefix) atomicAdd(&h[v.x & 0xFFu], 1u);
            if ((v.y >> 8) == prefix) atomicAdd(&h[v.y & 0xFFu], 1u);
            if ((v.z >> 8) == prefix) atomicAdd(&h[v.z & 0xFFu], 1u);
            if ((v.w >> 8) == prefix) atomicAdd(&h[v.w & 0xFFu], 1u);
        }
    }
    __syncthreads();
    for (int i = threadIdx.x; i < nb; i += 256) {
        unsigned c = h[i];
        if (c) atomicAdd(&gh[i], c);
    }
}

// Find bucket of k-th largest (suffix-scan from high buckets), update state.
__global__ __launch_bounds__(256) void scan_kernel(
    const unsigned* __restrict__ hist, unsigned* st, int level)
{
    __shared__ unsigned P[256];
    __shared__ int gsh;
    __shared__ unsigned cumAb;
    const int t = threadIdx.x;
    const int nb = (level == 2) ? 256 : 4096;
    const int s = nb >> 8;                 // 16 or 1
    const unsigned k = (level == 0) ? KSEL : st[1];

    unsigned ps = 0;
    for (int j = 0; j < s; ++j) ps += hist[t * s + j];
    P[t] = ps;
    __syncthreads();
    for (int off = 1; off < 256; off <<= 1) {
        unsigned v = P[t] + ((t + off < 256) ? P[t + off] : 0u);
        __syncthreads();
        P[t] = v;
        __syncthreads();
    }
    if (P[t] >= k && (t == 255 || P[t + 1] < k)) {
        gsh = t;
        cumAb = (t == 255) ? 0u : P[t + 1];
    }
    __syncthreads();
    if (t == 0) {
        int g = gsh;
        unsigned cum = cumAb, Bsel = 0, krem = k;
        for (int b = g * s + s - 1; b >= g * s; --b) {
            unsigned c = hist[b];
            if (cum + c >= k) { Bsel = (unsigned)b; krem = k - cum; break; }
            cum += c;
        }
        if (level == 0)      { st[0] = Bsel;               st[1] = krem; }
        else if (level == 1) { st[0] = (st[0] << 12) | Bsel; st[1] = krem; }
        else                 { st[2] = (st[0] << 8) | Bsel; }
    }
}

// ---------------------------------------------------------------------------
// 5) Final: topk kept as-is; remainder dropout-masked and scaled by 1/0.9.
// ---------------------------------------------------------------------------
__global__ __launch_bounds__(256) void final_kernel(
    float4* __restrict__ out, const float4* __restrict__ u4,
    const unsigned* __restrict__ st, unsigned n4)
{
    const float thr = __uint_as_float(st[2]);
    const unsigned stride = gridDim.x * blockDim.x;
    for (unsigned i = blockIdx.x * blockDim.x + threadIdx.x; i < n4; i += stride) {
        float4 a = out[i];
        float4 u = u4[i];
        float4 r;
        r.x = (a.x >= thr) ? a.x : ((u.x >= 0.1f) ? a.x * (1.0f / 0.9f) : 0.0f);
        r.y = (a.y >= thr) ? a.y : ((u.y >= 0.1f) ? a.y * (1.0f / 0.9f) : 0.0f);
        r.z = (a.z >= thr) ? a.z : ((u.z >= 0.1f) ? a.z * (1.0f / 0.9f) : 0.0f);
        r.w = (a.w >= thr) ? a.w : ((u.w >= 0.1f) ? a.w * (1.0f / 0.9f) : 0.0f);
        out[i] = r;
    }
}

extern "C" void kernel_launch(void* const* d_in, const int* in_sizes, int n_in,
                              void* d_out, int out_size, void* d_ws, size_t ws_size,
                              hipStream_t stream)
{
    const float* x  = (const float*)d_in[0];
    const float* WQ = (const float*)d_in[1];
    const float* WK = (const float*)d_in[2];
    const float* du = (const float*)d_in[3];
    float* out = (float*)d_out;
    char* ws = (char*)d_ws;

    float* Qc = (float*)(ws + OFF_QC);
    float* Kc = (float*)(ws + OFF_KC);
    unsigned* hA = (unsigned*)(ws + OFF_HA);
    unsigned* hB = (unsigned*)(ws + OFF_HB);
    unsigned* hC = (unsigned*)(ws + OFF_HC);
    unsigned* st = (unsigned*)(ws + OFF_ST);

    hipMemsetAsync(ws + OFF_HA, 0, ZERO_BYTES, stream);

    proj_kernel<<<256, 256, 0, stream>>>(x, WQ, WK, Qc, Kc);
    gemm_kernel<<<1024, 256, 0, stream>>>(Qc, Kc, out);
    softmax_kernel<<<NN, 256, 0, stream>>>(out);

    const unsigned n4 = (unsigned)(NN * NN) / 4u;
    hist_kernel<<<2048, 256, 0, stream>>>((const uint4*)out, n4, hA, 0, st);
    scan_kernel<<<1, 256, 0, stream>>>(hA, st, 0);
    hist_kernel<<<2048, 256, 0, stream>>>((const uint4*)out, n4, hB, 1, st);
    scan_kernel<<<1, 256, 0, stream>>>(hB, st, 1);
    hist_kernel<<<2048, 256, 0, stream>>>((const uint4*)out, n4, hC, 2, st);
    scan_kernel<<<1, 256, 0, stream>>>(hC, st, 2);

    final_kernel<<<2048, 256, 0, stream>>>((float4*)out, (const float4*)du, st, n4);
}

// Round 2
// 219.985 us; speedup vs baseline: 1.3263x; 1.3263x over previous
//
#include <hip/hip_runtime.h>
#include <stdint.h>

// Problem constants
#define NN 4096
#define KSEL 1677721u            // int(4096*4096*0.1)
#define INV_SQRT_DK 0.17677669529663687f  // 1/sqrt(32)

// Workspace layout (bytes)
#define OFF_QC 0                          // 4096*128 fp32 = 2 MB
#define OFF_KC (4096*128*4)               // 2 MB
#define OFF_HA (2*4096*128*4)             // hist level0: 4096 u32
#define OFF_HB (OFF_HA + 4096*4)          // hist level1: 4096 u32
#define OFF_ST (OFF_HB + 4096*4)          // state: 4 u32
#define ZERO_BYTES ((OFF_ST + 16) - OFF_HA)

// ---------------------------------------------------------------------------
// 1) Projection: Qcat[n][b*32+d] = sum_{t,f} x[b,f,n,t] * W_Q[t*64+f][d]
//    Block = (b, 64-row n-tile), 512 threads = 8 waves.
//    Reduction over f split 8-ways across waves (f-chunks of 8); each lane
//    owns one n-row and accumulates all 64 outputs (32 Q + 32 K) in regs.
//    x loads are direct global (12 contiguous floats/lane); W loads are
//    wave-uniform -> scalar. No barriers in the main loop; one LDS
//    tree-reduction at the end (4 col-quarter passes, 34 KB LDS).
// ---------------------------------------------------------------------------
__global__ __launch_bounds__(512) void proj_kernel(
    const float* __restrict__ x, const float* __restrict__ WQ,
    const float* __restrict__ WK, float* __restrict__ Qc, float* __restrict__ Kc)
{
    __shared__ float red[8 * 64 * 17];   // 34,816 B; pad 17 -> conflict-free
    const int b   = blockIdx.x >> 6;
    const int n0  = (blockIdx.x & 63) << 6;
    const int tid = threadIdx.x;
    const int l   = tid & 63;
    const int w   = __builtin_amdgcn_readfirstlane(tid >> 6); // 0..7, uniform
    const int n   = n0 + l;

    float accQ[32], accK[32];
#pragma unroll
    for (int j = 0; j < 32; ++j) { accQ[j] = 0.f; accK[j] = 0.f; }

    const float* xp = x + (size_t)b * 3145728 + (size_t)(w * 8) * 49152 + (size_t)n * 12;

    for (int f = 0; f < 8; ++f) {
        float4 a0 = *(const float4*)(xp);
        float4 a1 = *(const float4*)(xp + 4);
        float4 a2 = *(const float4*)(xp + 8);
        const float xv[12] = {a0.x, a0.y, a0.z, a0.w,
                              a1.x, a1.y, a1.z, a1.w,
                              a2.x, a2.y, a2.z, a2.w};
        const int fg = w * 8 + f;
#pragma unroll
        for (int t = 0; t < 12; ++t) {
            const float* __restrict__ wq = WQ + (size_t)(((t << 6) + fg) << 5);
            const float* __restrict__ wk = WK + (size_t)(((t << 6) + fg) << 5);
            const float xt = xv[t];
#pragma unroll
            for (int j = 0; j < 32; ++j) {
                accQ[j] = fmaf(xt, wq[j], accQ[j]);
                accK[j] = fmaf(xt, wk[j], accK[j]);
            }
        }
        xp += 49152;
    }

    // Cross-wave reduction: 4 passes over 16-column slices (Qlo,Qhi,Klo,Khi)
    for (int p = 0; p < 4; ++p) {
        const float* src = (p < 2) ? accQ : accK;
        const int off = (p & 1) << 4;
        float* rp = &red[(w * 64 + l) * 17];
#pragma unroll
        for (int j = 0; j < 16; ++j) rp[j] = src[off + j];
        __syncthreads();
        // 1024 outputs (64 rows x 16 cols), 512 threads -> 2 each
#pragma unroll
        for (int h = 0; h < 2; ++h) {
            int o = tid + h * 512;
            int r_ = o >> 4, c = o & 15;
            float s = 0.f;
#pragma unroll
            for (int w2 = 0; w2 < 8; ++w2) s += red[(w2 * 64 + r_) * 17 + c];
            if (p < 2)
                Qc[(size_t)(n0 + r_) * 128 + (b << 5) + (p << 4) + c] = s * INV_SQRT_DK;
            else
                Kc[(size_t)(n0 + r_) * 128 + (b << 5) + ((p - 2) << 4) + c] = s;
        }
        __syncthreads();
    }
}

// ---------------------------------------------------------------------------
// 2) S = Qc @ Kc^T  (4096x4096x128 fp32). 128x128 tile per 256-thread block,
//    8x8 acc per thread. LDS stored k-major with pad 132 (=4*33).
// ---------------------------------------------------------------------------
__global__ __launch_bounds__(256) void gemm_kernel(
    const float* __restrict__ Qc, const float* __restrict__ Kc,
    float* __restrict__ S)
{
    __shared__ float Qs[16 * 132];
    __shared__ float Ks[16 * 132];
    const int bi = blockIdx.x >> 5, bj = blockIdx.x & 31;
    const int tid = threadIdx.x;
    const int tr = tid >> 4, tc = tid & 15;
    const int kc4 = tid & 3, nr = tid >> 2;

    float acc[8][8];
#pragma unroll
    for (int i = 0; i < 8; ++i)
#pragma unroll
        for (int j = 0; j < 8; ++j) acc[i][j] = 0.f;

    const float* qbase = Qc + (size_t)(bi * 128) * 128;
    const float* kbase = Kc + (size_t)(bj * 128) * 128;

    for (int k0 = 0; k0 < 128; k0 += 16) {
        __syncthreads();
#pragma unroll
        for (int h = 0; h < 2; ++h) {
            int row = nr + h * 64;
            float4 q = *(const float4*)(qbase + (size_t)row * 128 + k0 + kc4 * 4);
            float4 kv = *(const float4*)(kbase + (size_t)row * 128 + k0 + kc4 * 4);
            Qs[(kc4 * 4 + 0) * 132 + row] = q.x;
            Qs[(kc4 * 4 + 1) * 132 + row] = q.y;
            Qs[(kc4 * 4 + 2) * 132 + row] = q.z;
            Qs[(kc4 * 4 + 3) * 132 + row] = q.w;
            Ks[(kc4 * 4 + 0) * 132 + row] = kv.x;
            Ks[(kc4 * 4 + 1) * 132 + row] = kv.y;
            Ks[(kc4 * 4 + 2) * 132 + row] = kv.z;
            Ks[(kc4 * 4 + 3) * 132 + row] = kv.w;
        }
        __syncthreads();
#pragma unroll
        for (int kk = 0; kk < 16; ++kk) {
            float4 a0 = *(const float4*)&Qs[kk * 132 + tr * 4];
            float4 a1 = *(const float4*)&Qs[kk * 132 + 64 + tr * 4];
            float4 b0 = *(const float4*)&Ks[kk * 132 + tc * 4];
            float4 b1 = *(const float4*)&Ks[kk * 132 + 64 + tc * 4];
            float a[8] = {a0.x, a0.y, a0.z, a0.w, a1.x, a1.y, a1.z, a1.w};
            float bb[8] = {b0.x, b0.y, b0.z, b0.w, b1.x, b1.y, b1.z, b1.w};
#pragma unroll
            for (int i = 0; i < 8; ++i)
#pragma unroll
                for (int j = 0; j < 8; ++j) acc[i][j] = fmaf(a[i], bb[j], acc[i][j]);
        }
    }
#pragma unroll
    for (int i = 0; i < 8; ++i) {
        int row = bi * 128 + tr * 4 + (i & 3) + ((i >> 2) << 6);
        float* dst = S + (size_t)row * NN + bj * 128;
        *(float4*)(dst + tc * 4)      = make_float4(acc[i][0], acc[i][1], acc[i][2], acc[i][3]);
        *(float4*)(dst + 64 + tc * 4) = make_float4(acc[i][4], acc[i][5], acc[i][6], acc[i][7]);
    }
}

// ---------------------------------------------------------------------------
// 3) Row softmax in place. One block per row; row staged in LDS.
// ---------------------------------------------------------------------------
__global__ __launch_bounds__(256) void softmax_kernel(float* __restrict__ S)
{
    __shared__ float xs[NN];
    __shared__ float red[8];
    const int tid = threadIdx.x;
    float* r = S + (size_t)blockIdx.x * NN;

    float lmax = -3.4e38f;
    for (int i = tid; i < NN / 4; i += 256) {
        float4 v = ((const float4*)r)[i];
        ((float4*)xs)[i] = v;
        lmax = fmaxf(fmaxf(fmaxf(lmax, v.x), v.y), fmaxf(v.z, v.w));
    }
#pragma unroll
    for (int off = 32; off; off >>= 1) lmax = fmaxf(lmax, __shfl_xor(lmax, off));
    if ((tid & 63) == 0) red[tid >> 6] = lmax;
    __syncthreads();
    const float m = fmaxf(fmaxf(red[0], red[1]), fmaxf(red[2], red[3]));

    float lsum = 0.f;
    for (int i = tid; i < NN / 4; i += 256) {
        float4 v = ((float4*)xs)[i];
        v.x = __expf(v.x - m); v.y = __expf(v.y - m);
        v.z = __expf(v.z - m); v.w = __expf(v.w - m);
        ((float4*)xs)[i] = v;
        lsum += v.x + v.y + v.z + v.w;
    }
#pragma unroll
    for (int off = 32; off; off >>= 1) lsum += __shfl_xor(lsum, off);
    if ((tid & 63) == 0) red[4 + (tid >> 6)] = lsum;
    __syncthreads();
    const float inv = 1.0f / (red[4] + red[5] + red[6] + red[7]);

    for (int i = tid; i < NN / 4; i += 256) {
        float4 v = ((float4*)xs)[i];
        v.x *= inv; v.y *= inv; v.z *= inv; v.w *= inv;
        ((float4*)r)[i] = v;
    }
}

// ---------------------------------------------------------------------------
// 4) Radix-select, 2 levels of 12 bits (24-bit threshold is exact enough:
//    k-th value <= 4096/1.68M = 2.4e-3, so any tie error << 1.48e-2 tol).
// ---------------------------------------------------------------------------
__global__ __launch_bounds__(256) void hist_kernel(
    const uint4* __restrict__ v4, unsigned n4, unsigned* __restrict__ gh,
    int level, const unsigned* __restrict__ st)
{
    __shared__ unsigned h[4096];
    for (int i = threadIdx.x; i < 4096; i += 256) h[i] = 0;
    const unsigned prefix = (level > 0) ? st[0] : 0u;
    __syncthreads();
    const unsigned stride = gridDim.x * blockDim.x;
    for (unsigned i = blockIdx.x * blockDim.x + threadIdx.x; i < n4; i += stride) {
        uint4 v = v4[i];
        if (level == 0) {
            atomicAdd(&h[v.x >> 20], 1u); atomicAdd(&h[v.y >> 20], 1u);
            atomicAdd(&h[v.z >> 20], 1u); atomicAdd(&h[v.w >> 20], 1u);
        } else {
            if ((v.x >> 20) == prefix) atomicAdd(&h[(v.x >> 8) & 0xFFFu], 1u);
            if ((v.y >> 20) == prefix) atomicAdd(&h[(v.y >> 8) & 0xFFFu], 1u);
            if ((v.z >> 20) == prefix) atomicAdd(&h[(v.z >> 8) & 0xFFFu], 1u);
            if ((v.w >> 20) == prefix) atomicAdd(&h[(v.w >> 8) & 0xFFFu], 1u);
        }
    }
    __syncthreads();
    for (int i = threadIdx.x; i < 4096; i += 256) {
        unsigned c = h[i];
        if (c) atomicAdd(&gh[i], c);
    }
}

// Find bucket of k-th largest (suffix-scan from high buckets), update state.
__global__ __launch_bounds__(256) void scan_kernel(
    const unsigned* __restrict__ hist, unsigned* st, int level)
{
    __shared__ unsigned P[256];
    __shared__ int gsh;
    __shared__ unsigned cumAb;
    const int t = threadIdx.x;
    const int s = 16;                      // 4096 bins -> 256 groups of 16
    const unsigned k = (level == 0) ? KSEL : st[1];

    unsigned ps = 0;
    for (int j = 0; j < s; ++j) ps += hist[t * s + j];
    P[t] = ps;
    __syncthreads();
    for (int off = 1; off < 256; off <<= 1) {
        unsigned v = P[t] + ((t + off < 256) ? P[t + off] : 0u);
        __syncthreads();
        P[t] = v;
        __syncthreads();
    }
    if (P[t] >= k && (t == 255 || P[t + 1] < k)) {
        gsh = t;
        cumAb = (t == 255) ? 0u : P[t + 1];
    }
    __syncthreads();
    if (t == 0) {
        int g = gsh;
        unsigned cum = cumAb, Bsel = 0, krem = k;
        for (int b = g * s + s - 1; b >= g * s; --b) {
            unsigned c = hist[b];
            if (cum + c >= k) { Bsel = (unsigned)b; krem = k - cum; break; }
            cum += c;
        }
        if (level == 0) { st[0] = Bsel; st[1] = krem; }
        else            { st[2] = ((st[0] << 12) | Bsel) << 8; }
    }
}

// ---------------------------------------------------------------------------
// 5) Final: topk kept as-is; remainder dropout-masked and scaled by 1/0.9.
// ---------------------------------------------------------------------------
__global__ __launch_bounds__(256) void final_kernel(
    float4* __restrict__ out, const float4* __restrict__ u4,
    const unsigned* __restrict__ st, unsigned n4)
{
    const float thr = __uint_as_float(st[2]);
    const unsigned stride = gridDim.x * blockDim.x;
    for (unsigned i = blockIdx.x * blockDim.x + threadIdx.x; i < n4; i += stride) {
        float4 a = out[i];
        float4 u = u4[i];
        float4 r;
        r.x = (a.x >= thr) ? a.x : ((u.x >= 0.1f) ? a.x * (1.0f / 0.9f) : 0.0f);
        r.y = (a.y >= thr) ? a.y : ((u.y >= 0.1f) ? a.y * (1.0f / 0.9f) : 0.0f);
        r.z = (a.z >= thr) ? a.z : ((u.z >= 0.1f) ? a.z * (1.0f / 0.9f) : 0.0f);
        r.w = (a.w >= thr) ? a.w : ((u.w >= 0.1f) ? a.w * (1.0f / 0.9f) : 0.0f);
        out[i] = r;
    }
}

extern "C" void kernel_launch(void* const* d_in, const int* in_sizes, int n_in,
                              void* d_out, int out_size, void* d_ws, size_t ws_size,
                              hipStream_t stream)
{
    const float* x  = (const float*)d_in[0];
    const float* WQ = (const float*)d_in[1];
    const float* WK = (const float*)d_in[2];
    const float* du = (const float*)d_in[3];
    float* out = (float*)d_out;
    char* ws = (char*)d_ws;

    float* Qc = (float*)(ws + OFF_QC);
    float* Kc = (float*)(ws + OFF_KC);
    unsigned* hA = (unsigned*)(ws + OFF_HA);
    unsigned* hB = (unsigned*)(ws + OFF_HB);
    unsigned* st = (unsigned*)(ws + OFF_ST);

    hipMemsetAsync(ws + OFF_HA, 0, ZERO_BYTES, stream);

    proj_kernel<<<256, 512, 0, stream>>>(x, WQ, WK, Qc, Kc);
    gemm_kernel<<<1024, 256, 0, stream>>>(Qc, Kc, out);
    softmax_kernel<<<NN, 256, 0, stream>>>(out);

    const unsigned n4 = (unsigned)(NN * NN) / 4u;
    hist_kernel<<<2048, 256, 0, stream>>>((const uint4*)out, n4, hA, 0, st);
    scan_kernel<<<1, 256, 0, stream>>>(hA, st, 0);
    hist_kernel<<<2048, 256, 0, stream>>>((const uint4*)out, n4, hB, 1, st);
    scan_kernel<<<1, 256, 0, stream>>>(hB, st, 1);

    final_kernel<<<2048, 256, 0, stream>>>((float4*)out, (const float4*)du, st, n4);
}

// Round 3
// 201.139 us; speedup vs baseline: 1.4506x; 1.0937x over previous
//
#include <hip/hip_runtime.h>
#include <stdint.h>

// Problem constants
#define NN 4096
#define KSEL 1677721u            // int(4096*4096*0.1)
#define INV_SQRT_DK 0.17677669529663687f  // 1/sqrt(32)

// Workspace layout (bytes)
#define OFF_QH 0                 // 4096*128 bf16 = 1 MB each
#define OFF_QL (1u<<20)
#define OFF_KH (2u<<20)
#define OFF_KL (3u<<20)
#define OFF_STATS (4u<<20)       // 4096 * float2 = 32 KB
#define OFF_H  (OFF_STATS + 32768u)   // 1024 u32 histogram
#define OFF_ST (OFF_H + 4096u)        // state: 4 u32
#define ZERO_BYTES (4096u + 16u)

typedef __attribute__((ext_vector_type(8))) short bf16x8;
typedef __attribute__((ext_vector_type(4))) float f32x4;

static __device__ __forceinline__ short f2bf(float f) {
    unsigned u = __float_as_uint(f);
    unsigned r = (u + 0x7FFFu + ((u >> 16) & 1u)) >> 16;   // RNE
    return (short)r;
}
static __device__ __forceinline__ float bf2f(short h) {
    return __uint_as_float(((unsigned)(unsigned short)h) << 16);
}

// ---------------------------------------------------------------------------
// 1) Projection -> Qhi/Qlo, Khi/Klo (bf16 split; Q carries 1/sqrt(32)).
//    Block = (b, 64-row n-tile), 512 threads = 8 waves; f-reduction split
//    across waves; LDS tree-reduce at the end.
// ---------------------------------------------------------------------------
__global__ __launch_bounds__(512) void proj_kernel(
    const float* __restrict__ x, const float* __restrict__ WQ,
    const float* __restrict__ WK,
    short* __restrict__ Qhi, short* __restrict__ Qlo,
    short* __restrict__ Khi, short* __restrict__ Klo)
{
    __shared__ float red[8 * 64 * 17];
    const int b   = blockIdx.x >> 6;
    const int n0  = (blockIdx.x & 63) << 6;
    const int tid = threadIdx.x;
    const int l   = tid & 63;
    const int w   = __builtin_amdgcn_readfirstlane(tid >> 6);
    const int n   = n0 + l;

    float accQ[32], accK[32];
#pragma unroll
    for (int j = 0; j < 32; ++j) { accQ[j] = 0.f; accK[j] = 0.f; }

    const float* xp = x + (size_t)b * 3145728 + (size_t)(w * 8) * 49152 + (size_t)n * 12;

    for (int f = 0; f < 8; ++f) {
        float4 a0 = *(const float4*)(xp);
        float4 a1 = *(const float4*)(xp + 4);
        float4 a2 = *(const float4*)(xp + 8);
        const float xv[12] = {a0.x, a0.y, a0.z, a0.w,
                              a1.x, a1.y, a1.z, a1.w,
                              a2.x, a2.y, a2.z, a2.w};
        const int fg = w * 8 + f;
#pragma unroll
        for (int t = 0; t < 12; ++t) {
            const float* __restrict__ wq = WQ + (size_t)(((t << 6) + fg) << 5);
            const float* __restrict__ wk = WK + (size_t)(((t << 6) + fg) << 5);
            const float xt = xv[t];
#pragma unroll
            for (int j = 0; j < 32; ++j) {
                accQ[j] = fmaf(xt, wq[j], accQ[j]);
                accK[j] = fmaf(xt, wk[j], accK[j]);
            }
        }
        xp += 49152;
    }

    for (int p = 0; p < 4; ++p) {
        const float* src = (p < 2) ? accQ : accK;
        const int off = (p & 1) << 4;
        float* rp = &red[(w * 64 + l) * 17];
#pragma unroll
        for (int j = 0; j < 16; ++j) rp[j] = src[off + j];
        __syncthreads();
#pragma unroll
        for (int h = 0; h < 2; ++h) {
            int o = tid + h * 512;
            int r_ = o >> 4, c = o & 15;
            float s = 0.f;
#pragma unroll
            for (int w2 = 0; w2 < 8; ++w2) s += red[(w2 * 64 + r_) * 17 + c];
            size_t idx = (size_t)(n0 + r_) * 128 + (b << 5) + ((p & 1) << 4) + c;
            if (p < 2) {
                float sv = s * INV_SQRT_DK;
                short hi = f2bf(sv);
                Qhi[idx] = hi;
                Qlo[idx] = f2bf(sv - bf2f(hi));
            } else {
                short hi = f2bf(s);
                Khi[idx] = hi;
                Klo[idx] = f2bf(s - bf2f(hi));
            }
        }
        __syncthreads();
    }
}

// ---------------------------------------------------------------------------
// 2) S = Q @ K^T via MFMA 16x16x32 bf16, 3-product hi/lo split.
//    128x128 tile per 256-thread block; wave -> 64x64 (4x4 frags); K=128.
//    Operands are L2-resident (4 MB total) -> no LDS staging.
// ---------------------------------------------------------------------------
__global__ __launch_bounds__(256) void gemm_kernel(
    const short* __restrict__ Qhi, const short* __restrict__ Qlo,
    const short* __restrict__ Khi, const short* __restrict__ Klo,
    float* __restrict__ S)
{
    const int bi = blockIdx.x >> 5, bj = blockIdx.x & 31;
    const int tid = threadIdx.x;
    const int w = tid >> 6, l = tid & 63;
    const int m0 = bi * 128 + (w >> 1) * 64;
    const int n0 = bj * 128 + (w & 1) * 64;
    const int lr = l & 15;
    const int kg = (l >> 4) * 8;

    f32x4 acc[4][4];
#pragma unroll
    for (int i = 0; i < 4; ++i)
#pragma unroll
        for (int j = 0; j < 4; ++j) acc[i][j] = (f32x4){0.f, 0.f, 0.f, 0.f};

    for (int k0 = 0; k0 < 128; k0 += 32) {
        bf16x8 ah[4], al[4], bh[4], bl[4];
#pragma unroll
        for (int i = 0; i < 4; ++i) {
            size_t qo = (size_t)(m0 + i * 16 + lr) * 128 + k0 + kg;
            size_t ko = (size_t)(n0 + i * 16 + lr) * 128 + k0 + kg;
            ah[i] = *(const bf16x8*)(Qhi + qo);
            al[i] = *(const bf16x8*)(Qlo + qo);
            bh[i] = *(const bf16x8*)(Khi + ko);
            bl[i] = *(const bf16x8*)(Klo + ko);
        }
#pragma unroll
        for (int i = 0; i < 4; ++i)
#pragma unroll
            for (int j = 0; j < 4; ++j) {
                acc[i][j] = __builtin_amdgcn_mfma_f32_16x16x32_bf16(ah[i], bh[j], acc[i][j], 0, 0, 0);
                acc[i][j] = __builtin_amdgcn_mfma_f32_16x16x32_bf16(ah[i], bl[j], acc[i][j], 0, 0, 0);
                acc[i][j] = __builtin_amdgcn_mfma_f32_16x16x32_bf16(al[i], bh[j], acc[i][j], 0, 0, 0);
            }
    }

    // C/D mapping (m89-verified): col = lane&15, row = (lane>>4)*4 + reg
#pragma unroll
    for (int i = 0; i < 4; ++i) {
        int rowb = m0 + i * 16 + (l >> 4) * 4;
#pragma unroll
        for (int j = 0; j < 4; ++j) {
            int col = n0 + j * 16 + (l & 15);
#pragma unroll
            for (int r = 0; r < 4; ++r)
                S[(size_t)(rowb + r) * NN + col] = acc[i][j][r];
        }
    }
}

// ---------------------------------------------------------------------------
// 3) Fused row stats + histogram. One block per row; row staged in LDS.
//    Online (max, sumexp) -> stats[row]; then bin p = exp(s-m)*inv into a
//    1024-bin linear-in-float-bits histogram over [2^-16, 2^-8).
// ---------------------------------------------------------------------------
__global__ __launch_bounds__(256) void histstat_kernel(
    const float* __restrict__ S, float2* __restrict__ stats,
    unsigned* __restrict__ gh)
{
    __shared__ float4 xs[1024];
    __shared__ unsigned h[1024];
    __shared__ float redm[4], reds[4];
    const int tid = threadIdx.x;
    const int row = blockIdx.x;
    const float4* r = (const float4*)(S + (size_t)row * NN);

    for (int i = tid; i < 1024; i += 256) h[i] = 0;

    float m = -3.4e38f, s = 0.f;
    for (int i = tid; i < 1024; i += 256) {
        float4 v = r[i];
        xs[i] = v;
        float mv = fmaxf(fmaxf(v.x, v.y), fmaxf(v.z, v.w));
        float m2 = fmaxf(m, mv);
        s = s * __expf(m - m2) + __expf(v.x - m2) + __expf(v.y - m2)
          + __expf(v.z - m2) + __expf(v.w - m2);
        m = m2;
    }
#pragma unroll
    for (int off = 32; off; off >>= 1) {
        float m2 = __shfl_xor(m, off), s2 = __shfl_xor(s, off);
        float mm = fmaxf(m, m2);
        s = s * __expf(m - mm) + s2 * __expf(m2 - mm);
        m = mm;
    }
    if ((tid & 63) == 0) { redm[tid >> 6] = m; reds[tid >> 6] = s; }
    __syncthreads();
    const float M = fmaxf(fmaxf(redm[0], redm[1]), fmaxf(redm[2], redm[3]));
    const float Ssum = reds[0] * __expf(redm[0] - M) + reds[1] * __expf(redm[1] - M)
                     + reds[2] * __expf(redm[2] - M) + reds[3] * __expf(redm[3] - M);
    const float inv = 1.0f / Ssum;
    if (tid == 0) stats[row] = make_float2(M, inv);

    for (int i = tid; i < 1024; i += 256) {
        float4 v = xs[i];
        float p0 = __expf(v.x - M) * inv;
        float p1 = __expf(v.y - M) * inv;
        float p2 = __expf(v.z - M) * inv;
        float p3 = __expf(v.w - M) * inv;
        int b0 = min(max((int)(__float_as_uint(p0) >> 16) - 0x3780, 0), 1023);
        int b1 = min(max((int)(__float_as_uint(p1) >> 16) - 0x3780, 0), 1023);
        int b2 = min(max((int)(__float_as_uint(p2) >> 16) - 0x3780, 0), 1023);
        int b3 = min(max((int)(__float_as_uint(p3) >> 16) - 0x3780, 0), 1023);
        atomicAdd(&h[b0], 1u); atomicAdd(&h[b1], 1u);
        atomicAdd(&h[b2], 1u); atomicAdd(&h[b3], 1u);
    }
    __syncthreads();
    for (int i = tid; i < 1024; i += 256) {
        unsigned c = h[i];
        if (c) atomicAdd(&gh[i], c);
    }
}

// ---------------------------------------------------------------------------
// 4) Suffix-scan over 1024 bins -> threshold bits in st[2].
// ---------------------------------------------------------------------------
__global__ __launch_bounds__(256) void scan_kernel(
    const unsigned* __restrict__ hist, unsigned* st)
{
    __shared__ unsigned P[256];
    __shared__ int gsh;
    __shared__ unsigned cumAb;
    const int t = threadIdx.x;
    const unsigned k = KSEL;

    unsigned ps = hist[t * 4] + hist[t * 4 + 1] + hist[t * 4 + 2] + hist[t * 4 + 3];
    P[t] = ps;
    __syncthreads();
    for (int off = 1; off < 256; off <<= 1) {
        unsigned v = P[t] + ((t + off < 256) ? P[t + off] : 0u);
        __syncthreads();
        P[t] = v;
        __syncthreads();
    }
    if (P[t] >= k && (t == 255 || P[t + 1] < k)) {
        gsh = t;
        cumAb = (t == 255) ? 0u : P[t + 1];
    }
    __syncthreads();
    if (t == 0) {
        int g = gsh;
        unsigned cum = cumAb, bsel = 0;
        for (int b = g * 4 + 3; b >= g * 4; --b) {
            unsigned c = hist[b];
            if (cum + c >= k) { bsel = (unsigned)b; break; }
            cum += c;
        }
        st[2] = (0x3780u + bsel) << 16;   // lower edge of selected bin
    }
}

// ---------------------------------------------------------------------------
// 5) Final: recompute p, threshold -> keep; else dropout (x1/0.9 or 0).
// ---------------------------------------------------------------------------
__global__ __launch_bounds__(256) void final_kernel(
    float* __restrict__ S, const float4* __restrict__ u4,
    const float2* __restrict__ stats, const unsigned* __restrict__ st)
{
    const int row = blockIdx.x;
    const float thr = __uint_as_float(st[2]);
    const float2 stt = stats[row];
    float4* r = (float4*)(S + (size_t)row * NN);
    const float4* u = u4 + (size_t)row * 1024;
    for (int i = threadIdx.x; i < 1024; i += 256) {
        float4 v = r[i];
        float4 uu = u[i];
        float4 o;
        float p;
        p = __expf(v.x - stt.x) * stt.y;
        o.x = (p >= thr) ? p : ((uu.x >= 0.1f) ? p * (1.0f / 0.9f) : 0.0f);
        p = __expf(v.y - stt.x) * stt.y;
        o.y = (p >= thr) ? p : ((uu.y >= 0.1f) ? p * (1.0f / 0.9f) : 0.0f);
        p = __expf(v.z - stt.x) * stt.y;
        o.z = (p >= thr) ? p : ((uu.z >= 0.1f) ? p * (1.0f / 0.9f) : 0.0f);
        p = __expf(v.w - stt.x) * stt.y;
        o.w = (p >= thr) ? p : ((uu.w >= 0.1f) ? p * (1.0f / 0.9f) : 0.0f);
        r[i] = o;
    }
}

extern "C" void kernel_launch(void* const* d_in, const int* in_sizes, int n_in,
                              void* d_out, int out_size, void* d_ws, size_t ws_size,
                              hipStream_t stream)
{
    const float* x  = (const float*)d_in[0];
    const float* WQ = (const float*)d_in[1];
    const float* WK = (const float*)d_in[2];
    const float* du = (const float*)d_in[3];
    float* out = (float*)d_out;
    char* ws = (char*)d_ws;

    short* Qhi = (short*)(ws + OFF_QH);
    short* Qlo = (short*)(ws + OFF_QL);
    short* Khi = (short*)(ws + OFF_KH);
    short* Klo = (short*)(ws + OFF_KL);
    float2* stats = (float2*)(ws + OFF_STATS);
    unsigned* hist = (unsigned*)(ws + OFF_H);
    unsigned* st = (unsigned*)(ws + OFF_ST);

    hipMemsetAsync(ws + OFF_H, 0, ZERO_BYTES, stream);

    proj_kernel<<<256, 512, 0, stream>>>(x, WQ, WK, Qhi, Qlo, Khi, Klo);
    gemm_kernel<<<1024, 256, 0, stream>>>(Qhi, Qlo, Khi, Klo, out);
    histstat_kernel<<<NN, 256, 0, stream>>>(out, stats, hist);
    scan_kernel<<<1, 256, 0, stream>>>(hist, st);
    final_kernel<<<NN, 256, 0, stream>>>(out, (const float4*)du, stats, st);
}

// Round 4
// 147.308 us; speedup vs baseline: 1.9807x; 1.3654x over previous
//
#include <hip/hip_runtime.h>
#include <stdint.h>

// Problem constants
#define NN 4096
#define KSEL 1677721u            // int(4096*4096*0.1)
#define INV_SQRT_DK 0.17677669529663687f  // 1/sqrt(32)

// Workspace layout (bytes)
#define OFF_QH 0                 // 4096*128 bf16 = 1 MB each
#define OFF_QL (1u<<20)
#define OFF_KH (2u<<20)
#define OFF_KL (3u<<20)
#define OFF_STATS (4u<<20)            // 4096 * float2 = 32 KB
#define OFF_H  (OFF_STATS + 32768u)   // 64 partial hists x 1024 u32 = 256 KB
#define OFF_ST (OFF_H + (64u*1024u*4u))  // state: 4 u32
#define ZERO_BYTES ((64u*1024u*4u) + 16u)

typedef __attribute__((ext_vector_type(8))) short bf16x8;
typedef __attribute__((ext_vector_type(4))) float f32x4;

static __device__ __forceinline__ short f2bf(float f) {
    unsigned u = __float_as_uint(f);
    unsigned r = (u + 0x7FFFu + ((u >> 16) & 1u)) >> 16;   // RNE
    return (short)r;
}
static __device__ __forceinline__ float bf2f(short h) {
    return __uint_as_float(((unsigned)(unsigned short)h) << 16);
}

// ---------------------------------------------------------------------------
// 1) Projection -> Qhi/Qlo, Khi/Klo (bf16 split; Q carries 1/sqrt(32)).
//    Block = (b, 64-row n-tile), 512 threads = 8 waves; f-reduction split
//    across waves; LDS tree-reduce at the end.
// ---------------------------------------------------------------------------
__global__ __launch_bounds__(512) void proj_kernel(
    const float* __restrict__ x, const float* __restrict__ WQ,
    const float* __restrict__ WK,
    short* __restrict__ Qhi, short* __restrict__ Qlo,
    short* __restrict__ Khi, short* __restrict__ Klo)
{
    __shared__ float red[8 * 64 * 17];
    const int b   = blockIdx.x >> 6;
    const int n0  = (blockIdx.x & 63) << 6;
    const int tid = threadIdx.x;
    const int l   = tid & 63;
    const int w   = __builtin_amdgcn_readfirstlane(tid >> 6);
    const int n   = n0 + l;

    float accQ[32], accK[32];
#pragma unroll
    for (int j = 0; j < 32; ++j) { accQ[j] = 0.f; accK[j] = 0.f; }

    const float* xp = x + (size_t)b * 3145728 + (size_t)(w * 8) * 49152 + (size_t)n * 12;

    for (int f = 0; f < 8; ++f) {
        float4 a0 = *(const float4*)(xp);
        float4 a1 = *(const float4*)(xp + 4);
        float4 a2 = *(const float4*)(xp + 8);
        const float xv[12] = {a0.x, a0.y, a0.z, a0.w,
                              a1.x, a1.y, a1.z, a1.w,
                              a2.x, a2.y, a2.z, a2.w};
        const int fg = w * 8 + f;
#pragma unroll
        for (int t = 0; t < 12; ++t) {
            const float* __restrict__ wq = WQ + (size_t)(((t << 6) + fg) << 5);
            const float* __restrict__ wk = WK + (size_t)(((t << 6) + fg) << 5);
            const float xt = xv[t];
#pragma unroll
            for (int j = 0; j < 32; ++j) {
                accQ[j] = fmaf(xt, wq[j], accQ[j]);
                accK[j] = fmaf(xt, wk[j], accK[j]);
            }
        }
        xp += 49152;
    }

    for (int p = 0; p < 4; ++p) {
        const float* src = (p < 2) ? accQ : accK;
        const int off = (p & 1) << 4;
        float* rp = &red[(w * 64 + l) * 17];
#pragma unroll
        for (int j = 0; j < 16; ++j) rp[j] = src[off + j];
        __syncthreads();
#pragma unroll
        for (int h = 0; h < 2; ++h) {
            int o = tid + h * 512;
            int r_ = o >> 4, c = o & 15;
            float s = 0.f;
#pragma unroll
            for (int w2 = 0; w2 < 8; ++w2) s += red[(w2 * 64 + r_) * 17 + c];
            size_t idx = (size_t)(n0 + r_) * 128 + (b << 5) + ((p & 1) << 4) + c;
            if (p < 2) {
                float sv = s * INV_SQRT_DK;
                short hi = f2bf(sv);
                Qhi[idx] = hi;
                Qlo[idx] = f2bf(sv - bf2f(hi));
            } else {
                short hi = f2bf(s);
                Khi[idx] = hi;
                Klo[idx] = f2bf(s - bf2f(hi));
            }
        }
        __syncthreads();
    }
}

// ---------------------------------------------------------------------------
// 2) S = Q @ K^T via MFMA 16x16x32 bf16, 3-product hi/lo split.
//    128x128 tile per 256-thread block; wave -> 64x64 (4x4 frags); K=128.
//    Operands are L2-resident (4 MB total) -> no LDS staging.
// ---------------------------------------------------------------------------
__global__ __launch_bounds__(256) void gemm_kernel(
    const short* __restrict__ Qhi, const short* __restrict__ Qlo,
    const short* __restrict__ Khi, const short* __restrict__ Klo,
    float* __restrict__ S)
{
    const int bi = blockIdx.x >> 5, bj = blockIdx.x & 31;
    const int tid = threadIdx.x;
    const int w = tid >> 6, l = tid & 63;
    const int m0 = bi * 128 + (w >> 1) * 64;
    const int n0 = bj * 128 + (w & 1) * 64;
    const int lr = l & 15;
    const int kg = (l >> 4) * 8;

    f32x4 acc[4][4];
#pragma unroll
    for (int i = 0; i < 4; ++i)
#pragma unroll
        for (int j = 0; j < 4; ++j) acc[i][j] = (f32x4){0.f, 0.f, 0.f, 0.f};

    for (int k0 = 0; k0 < 128; k0 += 32) {
        bf16x8 ah[4], al[4], bh[4], bl[4];
#pragma unroll
        for (int i = 0; i < 4; ++i) {
            size_t qo = (size_t)(m0 + i * 16 + lr) * 128 + k0 + kg;
            size_t ko = (size_t)(n0 + i * 16 + lr) * 128 + k0 + kg;
            ah[i] = *(const bf16x8*)(Qhi + qo);
            al[i] = *(const bf16x8*)(Qlo + qo);
            bh[i] = *(const bf16x8*)(Khi + ko);
            bl[i] = *(const bf16x8*)(Klo + ko);
        }
#pragma unroll
        for (int i = 0; i < 4; ++i)
#pragma unroll
            for (int j = 0; j < 4; ++j) {
                acc[i][j] = __builtin_amdgcn_mfma_f32_16x16x32_bf16(ah[i], bh[j], acc[i][j], 0, 0, 0);
                acc[i][j] = __builtin_amdgcn_mfma_f32_16x16x32_bf16(ah[i], bl[j], acc[i][j], 0, 0, 0);
                acc[i][j] = __builtin_amdgcn_mfma_f32_16x16x32_bf16(al[i], bh[j], acc[i][j], 0, 0, 0);
            }
    }

    // C/D mapping (m89-verified): col = lane&15, row = (lane>>4)*4 + reg
#pragma unroll
    for (int i = 0; i < 4; ++i) {
        int rowb = m0 + i * 16 + (l >> 4) * 4;
#pragma unroll
        for (int j = 0; j < 4; ++j) {
            int col = n0 + j * 16 + (l & 15);
#pragma unroll
            for (int r = 0; r < 4; ++r)
                S[(size_t)(rowb + r) * NN + col] = acc[i][j][r];
        }
    }
}

// ---------------------------------------------------------------------------
// 3) Fused row stats + histogram. ONE WAVE PER ROW, row held in registers
//    (16 float4/lane). Two register passes: max, then exp-overwrite + sum.
//    Butterfly shuffles for reductions; no LDS staging, no per-row syncs.
//    Block = 512 thr = 8 waves x 2 rows. Private 4 KB LDS hist per block,
//    merged into one of 64 global partial hists (low-contention atomics).
// ---------------------------------------------------------------------------
__global__ __launch_bounds__(512) void histstat_kernel(
    const float* __restrict__ S, float2* __restrict__ stats,
    unsigned* __restrict__ gh)
{
    __shared__ unsigned h[1024];
    const int tid = threadIdx.x;
    const int l = tid & 63;
    const int w = tid >> 6;

    for (int i = tid; i < 1024; i += 512) h[i] = 0;
    __syncthreads();

#pragma unroll
    for (int r = 0; r < 2; ++r) {
        const int row = (blockIdx.x << 4) + (r << 3) + w;
        const float4* rp = (const float4*)(S + (size_t)row * NN);

        float4 v[16];
#pragma unroll
        for (int j = 0; j < 16; ++j) v[j] = rp[l + (j << 6)];

        // pass 1: max
        float m = -3.4e38f;
#pragma unroll
        for (int j = 0; j < 16; ++j)
            m = fmaxf(m, fmaxf(fmaxf(v[j].x, v[j].y), fmaxf(v[j].z, v[j].w)));
#pragma unroll
        for (int off = 32; off; off >>= 1) m = fmaxf(m, __shfl_xor(m, off));

        // pass 2: exp overwrite + sum
        float s = 0.f;
#pragma unroll
        for (int j = 0; j < 16; ++j) {
            v[j].x = __expf(v[j].x - m); v[j].y = __expf(v[j].y - m);
            v[j].z = __expf(v[j].z - m); v[j].w = __expf(v[j].w - m);
            s += (v[j].x + v[j].y) + (v[j].z + v[j].w);
        }
#pragma unroll
        for (int off = 32; off; off >>= 1) s += __shfl_xor(s, off);
        const float inv = 1.0f / s;
        if (l == 0) stats[row] = make_float2(m, inv);

        // bin: p = e * inv, bin = top-16-bits(p) - bits(2^-16)>>16, clamped
#pragma unroll
        for (int j = 0; j < 16; ++j) {
            int b0 = min(max((int)(__float_as_uint(v[j].x * inv) >> 16) - 0x3780, 0), 1023);
            int b1 = min(max((int)(__float_as_uint(v[j].y * inv) >> 16) - 0x3780, 0), 1023);
            int b2 = min(max((int)(__float_as_uint(v[j].z * inv) >> 16) - 0x3780, 0), 1023);
            int b3 = min(max((int)(__float_as_uint(v[j].w * inv) >> 16) - 0x3780, 0), 1023);
            atomicAdd(&h[b0], 1u); atomicAdd(&h[b1], 1u);
            atomicAdd(&h[b2], 1u); atomicAdd(&h[b3], 1u);
        }
    }

    __syncthreads();
    unsigned* dst = gh + ((blockIdx.x & 63) << 10);
    for (int i = tid; i < 1024; i += 512) {
        unsigned c = h[i];
        if (c) atomicAdd(&dst[i], c);
    }
}

// ---------------------------------------------------------------------------
// 4) Reduce 64 partial hists + suffix-scan -> threshold bits in st[2].
// ---------------------------------------------------------------------------
__global__ __launch_bounds__(1024) void scan_kernel(
    const unsigned* __restrict__ gh, unsigned* st)
{
    __shared__ unsigned P[1024];
    const int t = threadIdx.x;
    unsigned s = 0;
    for (int p = 0; p < 64; ++p) s += gh[(p << 10) + t];
    P[t] = s;
    __syncthreads();
    for (int off = 1; off < 1024; off <<= 1) {
        unsigned v = P[t] + ((t + off < 1024) ? P[t + off] : 0u);
        __syncthreads();
        P[t] = v;
        __syncthreads();
    }
    // P[t] = count of elements with bin >= t
    if (P[t] >= KSEL && (t == 1023 || P[t + 1] < KSEL))
        st[2] = (0x3780u + (unsigned)t) << 16;   // lower edge of selected bin
}

// ---------------------------------------------------------------------------
// 5) Final: recompute p, threshold -> keep; else dropout (x1/0.9 or 0).
// ---------------------------------------------------------------------------
__global__ __launch_bounds__(256) void final_kernel(
    float* __restrict__ S, const float4* __restrict__ u4,
    const float2* __restrict__ stats, const unsigned* __restrict__ st)
{
    const int row = blockIdx.x;
    const float thr = __uint_as_float(st[2]);
    const float2 stt = stats[row];
    float4* r = (float4*)(S + (size_t)row * NN);
    const float4* u = u4 + (size_t)row * 1024;
    for (int i = threadIdx.x; i < 1024; i += 256) {
        float4 v = r[i];
        float4 uu = u[i];
        float4 o;
        float p;
        p = __expf(v.x - stt.x) * stt.y;
        o.x = (p >= thr) ? p : ((uu.x >= 0.1f) ? p * (1.0f / 0.9f) : 0.0f);
        p = __expf(v.y - stt.x) * stt.y;
        o.y = (p >= thr) ? p : ((uu.y >= 0.1f) ? p * (1.0f / 0.9f) : 0.0f);
        p = __expf(v.z - stt.x) * stt.y;
        o.z = (p >= thr) ? p : ((uu.z >= 0.1f) ? p * (1.0f / 0.9f) : 0.0f);
        p = __expf(v.w - stt.x) * stt.y;
        o.w = (p >= thr) ? p : ((uu.w >= 0.1f) ? p * (1.0f / 0.9f) : 0.0f);
        r[i] = o;
    }
}

extern "C" void kernel_launch(void* const* d_in, const int* in_sizes, int n_in,
                              void* d_out, int out_size, void* d_ws, size_t ws_size,
                              hipStream_t stream)
{
    const float* x  = (const float*)d_in[0];
    const float* WQ = (const float*)d_in[1];
    const float* WK = (const float*)d_in[2];
    const float* du = (const float*)d_in[3];
    float* out = (float*)d_out;
    char* ws = (char*)d_ws;

    short* Qhi = (short*)(ws + OFF_QH);
    short* Qlo = (short*)(ws + OFF_QL);
    short* Khi = (short*)(ws + OFF_KH);
    short* Klo = (short*)(ws + OFF_KL);
    float2* stats = (float2*)(ws + OFF_STATS);
    unsigned* hist = (unsigned*)(ws + OFF_H);
    unsigned* st = (unsigned*)(ws + OFF_ST);

    hipMemsetAsync(ws + OFF_H, 0, ZERO_BYTES, stream);

    proj_kernel<<<256, 512, 0, stream>>>(x, WQ, WK, Qhi, Qlo, Khi, Klo);
    gemm_kernel<<<1024, 256, 0, stream>>>(Qhi, Qlo, Khi, Klo, out);
    histstat_kernel<<<256, 512, 0, stream>>>(out, stats, hist);
    scan_kernel<<<1, 1024, 0, stream>>>(hist, st);
    final_kernel<<<NN, 256, 0, stream>>>(out, (const float4*)du, stats, st);
}

// Round 6
// 138.659 us; speedup vs baseline: 2.1043x; 1.0624x over previous
//
#include <hip/hip_runtime.h>
#include <stdint.h>

// Problem constants
#define NN 4096
#define KSEL 1677721u            // int(4096*4096*0.1)
#define INV_SQRT_DK 0.17677669529663687f  // 1/sqrt(32)

// Workspace layout (bytes)
#define OFF_P0 0                      // Qpart fp32 [2][4096*128] = 4 MB
#define OFF_P2 (4u<<20)               // Kpart fp32 [2][4096*128] = 4 MB
#define OFF_QH (8u<<20)               // bf16 1 MB each
#define OFF_QL (9u<<20)
#define OFF_KH (10u<<20)
#define OFF_KL (11u<<20)
#define OFF_STATS (12u<<20)           // 4096 * float2 = 32 KB
#define OFF_H  (OFF_STATS + 32768u)   // 64 partial hists x 1024 u32 = 256 KB
#define OFF_ST (OFF_H + (64u*1024u*4u))  // state: 4 u32
#define ZERO_BYTES ((64u*1024u*4u) + 16u)
#define HALF_ELEMS 524288u            // 4096*128

typedef __attribute__((ext_vector_type(8))) short bf16x8;
typedef __attribute__((ext_vector_type(4))) float f32x4;

static __device__ __forceinline__ short f2bf(float f) {
    unsigned u = __float_as_uint(f);
    unsigned r = (u + 0x7FFFu + ((u >> 16) & 1u)) >> 16;   // RNE
    return (short)r;
}
static __device__ __forceinline__ float bf2f(short h) {
    return __uint_as_float(((unsigned)(unsigned short)h) << 16);
}

// ---------------------------------------------------------------------------
// 1) Projection partial sums (fp32). Grid 512 = b(4) x ntile(64) x fhalf(2);
//    512 threads = 8 waves; each wave reduces an f-chunk of 4. 2 blocks/CU,
//    4 waves/SIMD to hide W scalar-load latency; launch_bounds(512,4) caps
//    VGPR at 128 so the 64 accumulators stay in registers.
// ---------------------------------------------------------------------------
__global__ __launch_bounds__(512, 4) void proj_kernel(
    const float* __restrict__ x, const float* __restrict__ WQ,
    const float* __restrict__ WK,
    float* __restrict__ Qp, float* __restrict__ Kp)
{
    __shared__ float red[8 * 64 * 17];
    const int bx  = blockIdx.x;
    const int b   = bx >> 7;
    const int n0  = ((bx >> 1) & 63) << 6;
    const int fs  = bx & 1;
    const int tid = threadIdx.x;
    const int l   = tid & 63;
    const int w   = __builtin_amdgcn_readfirstlane(tid >> 6);
    const int n   = n0 + l;

    float* __restrict__ Qdst = Qp + (size_t)fs * HALF_ELEMS;
    float* __restrict__ Kdst = Kp + (size_t)fs * HALF_ELEMS;

    float accQ[32], accK[32];
#pragma unroll
    for (int j = 0; j < 32; ++j) { accQ[j] = 0.f; accK[j] = 0.f; }

    const int fg0 = fs * 32 + w * 4;
    const float* xp = x + (size_t)b * 3145728 + (size_t)fg0 * 49152 + (size_t)n * 12;

    for (int f = 0; f < 4; ++f) {
        float4 a0 = *(const float4*)(xp);
        float4 a1 = *(const float4*)(xp + 4);
        float4 a2 = *(const float4*)(xp + 8);
        const float xv[12] = {a0.x, a0.y, a0.z, a0.w,
                              a1.x, a1.y, a1.z, a1.w,
                              a2.x, a2.y, a2.z, a2.w};
        const int fg = fg0 + f;
#pragma unroll
        for (int t = 0; t < 12; ++t) {
            const float* __restrict__ wq = WQ + (size_t)(((t << 6) + fg) << 5);
            const float* __restrict__ wk = WK + (size_t)(((t << 6) + fg) << 5);
            const float xt = xv[t];
#pragma unroll
            for (int j = 0; j < 32; ++j) {
                accQ[j] = fmaf(xt, wq[j], accQ[j]);
                accK[j] = fmaf(xt, wk[j], accK[j]);
            }
        }
        xp += 49152;
    }

    for (int p = 0; p < 4; ++p) {
        const float* src = (p < 2) ? accQ : accK;
        const int off = (p & 1) << 4;
        float* rp = &red[(w * 64 + l) * 17];
#pragma unroll
        for (int j = 0; j < 16; ++j) rp[j] = src[off + j];
        __syncthreads();
#pragma unroll
        for (int h = 0; h < 2; ++h) {
            int o = tid + h * 512;
            int r_ = o >> 4, c = o & 15;
            float s = 0.f;
#pragma unroll
            for (int w2 = 0; w2 < 8; ++w2) s += red[(w2 * 64 + r_) * 17 + c];
            size_t idx = (size_t)(n0 + r_) * 128 + (b << 5) + ((p & 1) << 4) + c;
            if (p < 2) Qdst[idx] = s; else Kdst[idx] = s;
        }
        __syncthreads();
    }
}

// ---------------------------------------------------------------------------
// 1b) Combine f-halves, scale Q, split to bf16 hi/lo.
//     524288 floats/matrix = 131072 float4 slots -> grid MUST be 512x256.
// ---------------------------------------------------------------------------
__global__ __launch_bounds__(256) void combine_kernel(
    const float4* __restrict__ Qp, const float4* __restrict__ Kp,
    short* __restrict__ Qhi, short* __restrict__ Qlo,
    short* __restrict__ Khi, short* __restrict__ Klo)
{
    const size_t i = (size_t)blockIdx.x * 256 + threadIdx.x;  // float4 slots
    float4 q0 = Qp[i], q1 = Qp[i + HALF_ELEMS / 4];
    float4 k0 = Kp[i], k1 = Kp[i + HALF_ELEMS / 4];
    float q[4] = {(q0.x + q1.x) * INV_SQRT_DK, (q0.y + q1.y) * INV_SQRT_DK,
                  (q0.z + q1.z) * INV_SQRT_DK, (q0.w + q1.w) * INV_SQRT_DK};
    float k[4] = {k0.x + k1.x, k0.y + k1.y, k0.z + k1.z, k0.w + k1.w};
    short4 qh, ql, kh, kl;
    qh.x = f2bf(q[0]); ql.x = f2bf(q[0] - bf2f(qh.x));
    qh.y = f2bf(q[1]); ql.y = f2bf(q[1] - bf2f(qh.y));
    qh.z = f2bf(q[2]); ql.z = f2bf(q[2] - bf2f(qh.z));
    qh.w = f2bf(q[3]); ql.w = f2bf(q[3] - bf2f(qh.w));
    kh.x = f2bf(k[0]); kl.x = f2bf(k[0] - bf2f(kh.x));
    kh.y = f2bf(k[1]); kl.y = f2bf(k[1] - bf2f(kh.y));
    kh.z = f2bf(k[2]); kl.z = f2bf(k[2] - bf2f(kh.z));
    kh.w = f2bf(k[3]); kl.w = f2bf(k[3] - bf2f(kh.w));
    *(short4*)(Qhi + 4 * i) = qh;
    *(short4*)(Qlo + 4 * i) = ql;
    *(short4*)(Khi + 4 * i) = kh;
    *(short4*)(Klo + 4 * i) = kl;
}

// ---------------------------------------------------------------------------
// 2) S = Q @ K^T via MFMA 16x16x32 bf16, 3-product hi/lo split.
// ---------------------------------------------------------------------------
__global__ __launch_bounds__(256) void gemm_kernel(
    const short* __restrict__ Qhi, const short* __restrict__ Qlo,
    const short* __restrict__ Khi, const short* __restrict__ Klo,
    float* __restrict__ S)
{
    const int bi = blockIdx.x >> 5, bj = blockIdx.x & 31;
    const int tid = threadIdx.x;
    const int w = tid >> 6, l = tid & 63;
    const int m0 = bi * 128 + (w >> 1) * 64;
    const int n0 = bj * 128 + (w & 1) * 64;
    const int lr = l & 15;
    const int kg = (l >> 4) * 8;

    f32x4 acc[4][4];
#pragma unroll
    for (int i = 0; i < 4; ++i)
#pragma unroll
        for (int j = 0; j < 4; ++j) acc[i][j] = (f32x4){0.f, 0.f, 0.f, 0.f};

    for (int k0 = 0; k0 < 128; k0 += 32) {
        bf16x8 ah[4], al[4], bh[4], bl[4];
#pragma unroll
        for (int i = 0; i < 4; ++i) {
            size_t qo = (size_t)(m0 + i * 16 + lr) * 128 + k0 + kg;
            size_t ko = (size_t)(n0 + i * 16 + lr) * 128 + k0 + kg;
            ah[i] = *(const bf16x8*)(Qhi + qo);
            al[i] = *(const bf16x8*)(Qlo + qo);
            bh[i] = *(const bf16x8*)(Khi + ko);
            bl[i] = *(const bf16x8*)(Klo + ko);
        }
#pragma unroll
        for (int i = 0; i < 4; ++i)
#pragma unroll
            for (int j = 0; j < 4; ++j) {
                acc[i][j] = __builtin_amdgcn_mfma_f32_16x16x32_bf16(ah[i], bh[j], acc[i][j], 0, 0, 0);
                acc[i][j] = __builtin_amdgcn_mfma_f32_16x16x32_bf16(ah[i], bl[j], acc[i][j], 0, 0, 0);
                acc[i][j] = __builtin_amdgcn_mfma_f32_16x16x32_bf16(al[i], bh[j], acc[i][j], 0, 0, 0);
            }
    }

    // C/D mapping (m89-verified): col = lane&15, row = (lane>>4)*4 + reg
#pragma unroll
    for (int i = 0; i < 4; ++i) {
        int rowb = m0 + i * 16 + (l >> 4) * 4;
#pragma unroll
        for (int j = 0; j < 4; ++j) {
            int col = n0 + j * 16 + (l & 15);
#pragma unroll
            for (int r = 0; r < 4; ++r)
                S[(size_t)(rowb + r) * NN + col] = acc[i][j][r];
        }
    }
}

// ---------------------------------------------------------------------------
// 3) Fused row stats + histogram. One wave per row, row in registers.
// ---------------------------------------------------------------------------
__global__ __launch_bounds__(512) void histstat_kernel(
    const float* __restrict__ S, float2* __restrict__ stats,
    unsigned* __restrict__ gh)
{
    __shared__ unsigned h[1024];
    const int tid = threadIdx.x;
    const int l = tid & 63;
    const int w = tid >> 6;

    for (int i = tid; i < 1024; i += 512) h[i] = 0;
    __syncthreads();

#pragma unroll
    for (int r = 0; r < 2; ++r) {
        const int row = (blockIdx.x << 4) + (r << 3) + w;
        const float4* rp = (const float4*)(S + (size_t)row * NN);

        float4 v[16];
#pragma unroll
        for (int j = 0; j < 16; ++j) v[j] = rp[l + (j << 6)];

        float m = -3.4e38f;
#pragma unroll
        for (int j = 0; j < 16; ++j)
            m = fmaxf(m, fmaxf(fmaxf(v[j].x, v[j].y), fmaxf(v[j].z, v[j].w)));
#pragma unroll
        for (int off = 32; off; off >>= 1) m = fmaxf(m, __shfl_xor(m, off));

        float s = 0.f;
#pragma unroll
        for (int j = 0; j < 16; ++j) {
            v[j].x = __expf(v[j].x - m); v[j].y = __expf(v[j].y - m);
            v[j].z = __expf(v[j].z - m); v[j].w = __expf(v[j].w - m);
            s += (v[j].x + v[j].y) + (v[j].z + v[j].w);
        }
#pragma unroll
        for (int off = 32; off; off >>= 1) s += __shfl_xor(s, off);
        const float inv = 1.0f / s;
        if (l == 0) stats[row] = make_float2(m, inv);

#pragma unroll
        for (int j = 0; j < 16; ++j) {
            int b0 = min(max((int)(__float_as_uint(v[j].x * inv) >> 16) - 0x3780, 0), 1023);
            int b1 = min(max((int)(__float_as_uint(v[j].y * inv) >> 16) - 0x3780, 0), 1023);
            int b2 = min(max((int)(__float_as_uint(v[j].z * inv) >> 16) - 0x3780, 0), 1023);
            int b3 = min(max((int)(__float_as_uint(v[j].w * inv) >> 16) - 0x3780, 0), 1023);
            atomicAdd(&h[b0], 1u); atomicAdd(&h[b1], 1u);
            atomicAdd(&h[b2], 1u); atomicAdd(&h[b3], 1u);
        }
    }

    __syncthreads();
    unsigned* dst = gh + ((blockIdx.x & 63) << 10);
    for (int i = tid; i < 1024; i += 512) {
        unsigned c = h[i];
        if (c) atomicAdd(&dst[i], c);
    }
}

// ---------------------------------------------------------------------------
// 4) Reduce 64 partial hists + suffix-scan -> threshold bits in st[2].
// ---------------------------------------------------------------------------
__global__ __launch_bounds__(1024) void scan_kernel(
    const unsigned* __restrict__ gh, unsigned* st)
{
    __shared__ unsigned P[1024];
    const int t = threadIdx.x;
    unsigned s = 0;
    for (int p = 0; p < 64; ++p) s += gh[(p << 10) + t];
    P[t] = s;
    __syncthreads();
    for (int off = 1; off < 1024; off <<= 1) {
        unsigned v = P[t] + ((t + off < 1024) ? P[t + off] : 0u);
        __syncthreads();
        P[t] = v;
        __syncthreads();
    }
    if (P[t] >= KSEL && (t == 1023 || P[t + 1] < KSEL))
        st[2] = (0x3780u + (unsigned)t) << 16;   // lower edge of selected bin
}

// ---------------------------------------------------------------------------
// 5) Final: recompute p, threshold -> keep; else dropout (x1/0.9 or 0).
// ---------------------------------------------------------------------------
__global__ __launch_bounds__(256) void final_kernel(
    float* __restrict__ S, const float4* __restrict__ u4,
    const float2* __restrict__ stats, const unsigned* __restrict__ st)
{
    const int row = blockIdx.x;
    const float thr = __uint_as_float(st[2]);
    const float2 stt = stats[row];
    float4* r = (float4*)(S + (size_t)row * NN);
    const float4* u = u4 + (size_t)row * 1024;
    for (int i = threadIdx.x; i < 1024; i += 256) {
        float4 v = r[i];
        float4 uu = u[i];
        float4 o;
        float p;
        p = __expf(v.x - stt.x) * stt.y;
        o.x = (p >= thr) ? p : ((uu.x >= 0.1f) ? p * (1.0f / 0.9f) : 0.0f);
        p = __expf(v.y - stt.x) * stt.y;
        o.y = (p >= thr) ? p : ((uu.y >= 0.1f) ? p * (1.0f / 0.9f) : 0.0f);
        p = __expf(v.z - stt.x) * stt.y;
        o.z = (p >= thr) ? p : ((uu.z >= 0.1f) ? p * (1.0f / 0.9f) : 0.0f);
        p = __expf(v.w - stt.x) * stt.y;
        o.w = (p >= thr) ? p : ((uu.w >= 0.1f) ? p * (1.0f / 0.9f) : 0.0f);
        r[i] = o;
    }
}

extern "C" void kernel_launch(void* const* d_in, const int* in_sizes, int n_in,
                              void* d_out, int out_size, void* d_ws, size_t ws_size,
                              hipStream_t stream)
{
    const float* x  = (const float*)d_in[0];
    const float* WQ = (const float*)d_in[1];
    const float* WK = (const float*)d_in[2];
    const float* du = (const float*)d_in[3];
    float* out = (float*)d_out;
    char* ws = (char*)d_ws;

    float* Qp = (float*)(ws + OFF_P0);
    float* Kp = (float*)(ws + OFF_P2);
    short* Qhi = (short*)(ws + OFF_QH);
    short* Qlo = (short*)(ws + OFF_QL);
    short* Khi = (short*)(ws + OFF_KH);
    short* Klo = (short*)(ws + OFF_KL);
    float2* stats = (float2*)(ws + OFF_STATS);
    unsigned* hist = (unsigned*)(ws + OFF_H);
    unsigned* st = (unsigned*)(ws + OFF_ST);

    hipMemsetAsync(ws + OFF_H, 0, ZERO_BYTES, stream);

    proj_kernel<<<512, 512, 0, stream>>>(x, WQ, WK, Qp, Kp);
    combine_kernel<<<512, 256, 0, stream>>>(
        (const float4*)Qp, (const float4*)Kp, Qhi, Qlo, Khi, Klo);
    gemm_kernel<<<1024, 256, 0, stream>>>(Qhi, Qlo, Khi, Klo, out);
    histstat_kernel<<<256, 512, 0, stream>>>(out, stats, hist);
    scan_kernel<<<1, 1024, 0, stream>>>(hist, st);
    final_kernel<<<NN, 256, 0, stream>>>(out, (const float4*)du, stats, st);
}